// Round 5
// baseline (788.282 us; speedup 1.0000x reference)
//
#include <hip/hip_runtime.h>

#define B_     4
#define T_     4096
#define C_     1024
#define H_     4096
#define BT_    (B_ * T_)
#define NCH_   64
#define CHLEN_ 64
#define MCHUNK 8192   // rows per h-chunk for GEMM2a/2b (2 chunks)

typedef __bf16 bf16_t;
typedef __bf16 bf16x8 __attribute__((ext_vector_type(8)));
typedef float  f32x4  __attribute__((ext_vector_type(4)));

__device__ __forceinline__ float hs_f(float v) {
    return fminf(fmaxf((v + 3.0f) * (1.0f / 6.0f), 0.0f), 1.0f) - 0.5f;
}

__device__ __forceinline__ void gld_lds16(const bf16_t* g, bf16_t* l) {
    __builtin_amdgcn_global_load_lds((const __attribute__((address_space(1))) void*)g,
                                     (__attribute__((address_space(3))) void*)l,
                                     16, 0, 0);
}

// ---------------------------------------------------------------------------
__global__ __launch_bounds__(256) void rms_rows_f32(const float* __restrict__ X,
                                                    float* __restrict__ inv) {
    const int wave = threadIdx.x >> 6, lane = threadIdx.x & 63;
    const int row = blockIdx.x * 4 + wave;
    const float* xr = X + (size_t)row * C_;
    float s = 0.0f;
    #pragma unroll
    for (int p = 0; p < 4; p++) {
        float4 v = *(const float4*)(xr + p * 256 + lane * 4);
        s += v.x * v.x + v.y * v.y + v.z * v.z + v.w * v.w;
    }
    #pragma unroll
    for (int o = 32; o > 0; o >>= 1) s += __shfl_down(s, o, 64);
    if (lane == 0) inv[row] = rsqrtf(s * (1.0f / C_) + 1e-6f);
}

__global__ __launch_bounds__(256) void rms_rows_bf16(const bf16_t* __restrict__ X,
                                                     float* __restrict__ inv) {
    const int wave = threadIdx.x >> 6, lane = threadIdx.x & 63;
    const int row = blockIdx.x * 4 + wave;
    const bf16_t* xr = X + (size_t)row * C_;
    bf16x8 v0 = *(const bf16x8*)(xr + lane * 8);
    bf16x8 v1 = *(const bf16x8*)(xr + 512 + lane * 8);
    float s = 0.0f;
    #pragma unroll
    for (int j = 0; j < 8; j++) {
        float a = (float)v0[j], b = (float)v1[j];
        s += a * a + b * b;
    }
    #pragma unroll
    for (int o = 32; o > 0; o >>= 1) s += __shfl_down(s, o, 64);
    if (lane == 0) inv[row] = rsqrtf(s * (1.0f / C_) + 1e-6f);
}

// ---------------------------------------------------------------------------
__global__ __launch_bounds__(256) void scan_emit_local(const float* __restrict__ X,
                                                       const float* __restrict__ inv1,
                                                       const float* __restrict__ nw,
                                                       bf16_t* __restrict__ state,
                                                       float* __restrict__ csum) {
    const int bch = blockIdx.x;
    const int b = bch >> 6, ch = bch & 63;
    const int c = blockIdx.y * 256 + threadIdx.x;
    const float wgt = nw[c];
    const int rbase = b * T_ + ch * CHLEN_;
    const size_t xbase = (size_t)rbase * C_ + c;
    float acc = 0.0f;
    for (int i = 0; i < CHLEN_; i++) {
        acc += hs_f(X[xbase + (size_t)i * C_] * inv1[rbase + i] * wgt);
        state[(size_t)(rbase + i) * C_ + c] = (bf16_t)acc;
    }
    csum[(size_t)bch * C_ + c] = acc;
}

__global__ __launch_bounds__(256) void scan_offsets_hilo(const float* __restrict__ csum,
                                                         bf16_t* __restrict__ hilo) {
    const int idx = blockIdx.x * 256 + threadIdx.x;   // b*1024 + c
    const int b = idx >> 10, c = idx & 1023;
    const size_t base = (size_t)b * NCH_ * C_ + c;
    float v[NCH_];
    #pragma unroll
    for (int ch = 0; ch < NCH_; ch++)
        v[ch] = csum[base + (size_t)ch * C_];
    float run = 0.0f;
    #pragma unroll
    for (int ch = 0; ch < NCH_; ch++) {
        const size_t row = (size_t)(b * NCH_ + ch) * 2048 + c;
        const bf16_t hi = (bf16_t)run;
        hilo[row] = hi;
        hilo[row + 1024] = (bf16_t)(run - (float)hi);
        run += v[ch];
    }
}

__global__ __launch_bounds__(256) void pmat_init(const float* __restrict__ b1,
                                                 float* __restrict__ Pmat) {
    const int i = blockIdx.x * 256 + threadIdx.x;
    Pmat[i] = b1[i & (C_ - 1)];
}

// ---------------------------------------------------------------------------
__global__ __launch_bounds__(256) void transpose_scale(const float* __restrict__ src,
                                                       bf16_t* __restrict__ dst,
                                                       int K, int N, int ldd, int dupOff,
                                                       const float* __restrict__ scale) {
    __shared__ float tile[32][33];
    const int n0 = blockIdx.x * 32, k0 = blockIdx.y * 32;
    const int tx = threadIdx.x & 31, ty = threadIdx.x >> 5;
    #pragma unroll
    for (int j = 0; j < 4; j++) {
        const int kk = ty + j * 8;
        float v = src[(size_t)(k0 + kk) * N + n0 + tx];
        if (scale) v *= scale[k0 + kk];
        tile[kk][tx] = v;
    }
    __syncthreads();
    #pragma unroll
    for (int j = 0; j < 4; j++) {
        const int nn = ty + j * 8;
        const bf16_t v = (bf16_t)tile[tx][nn];
        dst[(size_t)(n0 + nn) * ldd + k0 + tx] = v;
        if (dupOff) dst[(size_t)(n0 + nn) * ldd + dupOff + k0 + tx] = v;
    }
}

// ---------------------------------------------------------------------------
// 128x128 2-barrier GEMM, kept ONLY for the tiny split-K P-GEMM (atomicAdd).
// ---------------------------------------------------------------------------
__global__ __launch_bounds__(256) void gemm_pk(const bf16_t* __restrict__ A,
                                               const bf16_t* __restrict__ Bt,
                                               float* __restrict__ Cmat,
                                               int N, int K, int lda, int ldb) {
    __shared__ __align__(16) bf16_t As[128 * 32];
    __shared__ __align__(16) bf16_t Bs[128 * 32];
    const int tid = threadIdx.x;
    const int mBase = blockIdx.x * 128;
    const int nBase = blockIdx.y * 128;
    const size_t kOff = (size_t)blockIdx.z * K;

    const int wave = tid >> 6;
    const int lane = tid & 63;
    const int waveM = (wave & 1) * 64;
    const int waveN = (wave >> 1) * 64;
    const int lr = lane & 15;
    const int lq = lane >> 4;

    f32x4 acc[4][4] = {};

    const int e0 = tid * 8;
    const int r0 = e0 >> 5, c0 = e0 & 31;
    const int e1 = 2048 + tid * 8;
    const int r1 = e1 >> 5, c1 = e1 & 31;

    const bf16_t* Ag0 = A + (size_t)(mBase + r0) * lda + kOff + c0;
    const bf16_t* Ag1 = A + (size_t)(mBase + r1) * lda + kOff + c1;
    const bf16_t* Bg0 = Bt + (size_t)(nBase + r0) * ldb + kOff + c0;
    const bf16_t* Bg1 = Bt + (size_t)(nBase + r1) * ldb + kOff + c1;

    for (int kb = 0; kb < K; kb += 32) {
        __syncthreads();
        gld_lds16(Ag0 + kb, As + e0);
        gld_lds16(Ag1 + kb, As + e1);
        gld_lds16(Bg0 + kb, Bs + e0);
        gld_lds16(Bg1 + kb, Bs + e1);
        __syncthreads();

        bf16x8 af[4], bfr[4];
        #pragma unroll
        for (int mi = 0; mi < 4; mi++)
            af[mi] = *(const bf16x8*)(As + (waveM + mi * 16 + lr) * 32 + lq * 8);
        #pragma unroll
        for (int ni = 0; ni < 4; ni++)
            bfr[ni] = *(const bf16x8*)(Bs + (waveN + ni * 16 + lr) * 32 + lq * 8);
        #pragma unroll
        for (int mi = 0; mi < 4; mi++)
            #pragma unroll
            for (int ni = 0; ni < 4; ni++)
                acc[mi][ni] = __builtin_amdgcn_mfma_f32_16x16x32_bf16(
                    af[mi], bfr[ni], acc[mi][ni], 0, 0, 0);
    }

    #pragma unroll
    for (int ni = 0; ni < 4; ni++) {
        const int n = nBase + waveN + ni * 16 + lr;
        #pragma unroll
        for (int mi = 0; mi < 4; mi++) {
            #pragma unroll
            for (int r = 0; r < 4; r++) {
                const int m = mBase + waveM + mi * 16 + lq * 4 + r;
                atomicAdd(&Cmat[(size_t)m * N + n], acc[mi][ni][r]);
            }
        }
    }
}

// ---------------------------------------------------------------------------
// 256x256 8-phase bf16 GEMM (T1+T2+T3+T4+T5). 512 thr = 8 waves (2M x 4N),
// per-wave 128x64 out, BK=64. LDS = 2 dbuf x {A[256x64] + B[256x64]} bf16
// = 128 KiB (fits 160; 1 block/CU).  [R3 FIX: previous rev declared 256 KiB]
//
// Row = 128 B = 8 x 16B slots. T2 swizzle: phys slot s' = s ^ (row&7);
// staging pre-swizzles the GLOBAL source col, LDS dest stays linear
// (global_load_lds writes uniform+lane*16; verified no wave-load crosses a
// row-group boundary), ds_read applies the same XOR (rule #21).
//
// Phases p=0..7 per iteration (2 K-tiles of 64; buffer = K-tile parity):
// compute quadrant (mh=(p>>1)&1, nh=p&1) of K-tile 2it (p<4, buf0) then
// 2it+1 (p>=4, buf1): 12 ds_read_b128 + 16 MFMA each.
// Read-parity half-tiles (16 KiB = 2 gld_lds16/thr):
//   A_even = rows [0,64)+[128,192)  (read only at mh=0 phases)
//   A_odd  = rows [64,128)+[192,256)       (mh=1)
//   B_even = rows {g*64+[0,32)}            (nh=0)   B_odd = +32   (nh=1)
// Stage schedule (target @ K-tile): p0:b1.Ao@2it+1  p1:b1.Bo@2it+1
//   p2:b0.Ae@2it+2  p3:b0.Be@2it+2  p4:b0.Ao@2it+2  p5:b0.Bo@2it+2
//   p6:b1.Ae@2it+3  p7:b1.Be@2it+3
// Waits: vmcnt(4) after p3's stage and after p7's stage ONLY (T4, never 0
// in steady state). Each stage retires at the wait before its first read
// and is issued after the barrier following its region's last read
// (verified per-phase). Prologue: b0 x4 @k0 + b1.{Ae,Be} @k64, vmcnt(4).
//
// K accumulated in ascending 32-groups -> bitwise-identical to the old
// BK=32 kernel.
//
// MODE 0: out bf16 = hs(acc + pmat[(m>>6)*N+n]) * xf32[m*N+n]   (GEMM1)
// MODE 1: out bf16 = relu(rowscale[m]*acc + bias[n])            (GEMM2a)
// MODE 2: out f32  = acc + bias[n] + (f32)extra_bf16[m*N+n]     (GEMM2b)
// ---------------------------------------------------------------------------
template <int MODE, typename ET, typename OT>
__global__ __launch_bounds__(512, 2) void gemm256(const bf16_t* __restrict__ A,
                                                  const bf16_t* __restrict__ Bt,
                                                  const float* __restrict__ bias,
                                                  const ET* __restrict__ extra,
                                                  const float* __restrict__ rowscale,
                                                  const float* __restrict__ pmat,
                                                  OT* __restrict__ Cmat,
                                                  int N, int K, int lda, int ldb) {
    __shared__ __align__(16) bf16_t lds[2][2][256 * 64];   // 128 KiB

    const int tid = threadIdx.x;
    const int wave = tid >> 6, lane = tid & 63;
    const int wm = wave >> 2;          // 0..1  M half
    const int wn = wave & 3;           // 0..3  N quarter
    const int lr = lane & 15;
    const int lq = lane >> 4;

    // XCD m-slice tile mapping (R3 win, kept).
    const int nwgx = gridDim.x;
    const int flat0 = blockIdx.y * nwgx + blockIdx.x;
    int mTile, nTile;
    if ((nwgx & 7) == 0) {
        const int xcd = flat0 & 7;
        const int loc = flat0 >> 3;
        const int mpx = nwgx >> 3;
        mTile = xcd * mpx + (loc % mpx);
        nTile = loc / mpx;
    } else {
        mTile = blockIdx.x;
        nTile = blockIdx.y;
    }
    const int mBase = mTile * 256;
    const int nBase = nTile * 256;

    const bf16_t* Abase = A + (size_t)mBase * lda;
    const bf16_t* Bbase = Bt + (size_t)nBase * ldb;

    // Stage one read-parity half-tile (2 x gld_lds16/thread).
    auto stage = [&](int buf, int arr, int odd, int kb) {
        #pragma unroll
        for (int j = 0; j < 2; j++) {
            const int ps = tid + (j << 9);       // 0..1023
            const int s  = ps & 7;               // phys 16B slot in row
            const int q  = ps >> 3;              // 0..127
            int row;
            if (arr == 0) row = ((q >> 6) << 7) | (odd << 6) | (q & 63);
            else          row = ((q >> 5) << 6) | (odd << 5) | (q & 31);
            const int c = (s ^ (row & 7)) << 3;  // pre-swizzled source col
            const bf16_t* src = (arr == 0 ? Abase + (size_t)row * lda
                                          : Bbase + (size_t)row * ldb) + kb + c;
            gld_lds16(src, &lds[buf][arr][row * 64 + s * 8]);
        }
    };

    f32x4 acc[8][4] = {};

    // Prologue: buf0 all 4 halves @k=0; buf1 even halves @k=64.
    stage(0, 0, 0, 0); stage(0, 1, 0, 0); stage(0, 0, 1, 0); stage(0, 1, 1, 0);
    stage(1, 0, 0, 64); stage(1, 1, 0, 64);
    asm volatile("s_waitcnt vmcnt(4)" ::: "memory");   // buf0 retired; buf1 in flight
    __builtin_amdgcn_s_barrier();

    const int NIT = K >> 7;   // 2 K-tiles of 64 per iteration
    for (int it = 0; it < NIT; ++it) {
        const bool nl = (it + 1 < NIT);
        const int k1 = ((it << 1) + 1) << 6;
        const int k2 = ((it << 1) + 2) << 6;
        const int k3 = ((it << 1) + 3) << 6;

        #pragma unroll
        for (int p = 0; p < 8; ++p) {
            const int buf = p >> 2;              // compute buffer (K-tile parity)
            const int mh = (p >> 1) & 1, nh = p & 1;
            const bf16_t* At = &lds[buf][0][0];
            const bf16_t* Bl = &lds[buf][1][0];

            // 12 ds_read_b128 (XOR-swizzled)
            bf16x8 af[4][2], bfr[2][2];
            #pragma unroll
            for (int mi = 0; mi < 4; mi++) {
                const int R = wm * 128 + mh * 64 + mi * 16 + lr;
                const size_t rb = (size_t)R * 64;
                #pragma unroll
                for (int ks = 0; ks < 2; ks++)
                    af[mi][ks] = *(const bf16x8*)(At + rb + ((((ks << 2) | lq) ^ (R & 7)) << 3));
            }
            #pragma unroll
            for (int ni = 0; ni < 2; ni++) {
                const int R = wn * 64 + nh * 32 + ni * 16 + lr;
                const size_t rb = (size_t)R * 64;
                #pragma unroll
                for (int ks = 0; ks < 2; ks++)
                    bfr[ni][ks] = *(const bf16x8*)(Bl + rb + ((((ks << 2) | lq) ^ (R & 7)) << 3));
            }

            // stage one half-tile of a future K-tile
            switch (p) {
                case 0: stage(1, 0, 1, k1); break;
                case 1: stage(1, 1, 1, k1); break;
                case 2: if (nl) stage(0, 0, 0, k2); break;
                case 3: if (nl) stage(0, 1, 0, k2); break;
                case 4: if (nl) stage(0, 0, 1, k2); break;
                case 5: if (nl) stage(0, 1, 1, k2); break;
                case 6: if (nl) stage(1, 0, 0, k3); break;
                case 7: if (nl) stage(1, 1, 0, k3); break;
            }
            if (p == 3) {
                if (nl) asm volatile("s_waitcnt vmcnt(4)" ::: "memory");
                else    asm volatile("s_waitcnt vmcnt(0)" ::: "memory");
            }
            if (p == 7 && nl) asm volatile("s_waitcnt vmcnt(4)" ::: "memory");

            __builtin_amdgcn_s_barrier();
            __builtin_amdgcn_s_setprio(1);
            #pragma unroll
            for (int mi = 0; mi < 4; mi++)
                #pragma unroll
                for (int ni = 0; ni < 2; ni++) {
                    acc[mh * 4 + mi][nh * 2 + ni] = __builtin_amdgcn_mfma_f32_16x16x32_bf16(
                        af[mi][0], bfr[ni][0], acc[mh * 4 + mi][nh * 2 + ni], 0, 0, 0);
                    acc[mh * 4 + mi][nh * 2 + ni] = __builtin_amdgcn_mfma_f32_16x16x32_bf16(
                        af[mi][1], bfr[ni][1], acc[mh * 4 + mi][nh * 2 + ni], 0, 0, 0);
                }
            __builtin_amdgcn_s_setprio(0);
            __builtin_amdgcn_s_barrier();
        }
    }

    // Epilogue. C/D layout: col(n)=lane&15, row(m)=(lane>>4)*4+reg.
    #pragma unroll
    for (int fn = 0; fn < 4; fn++) {
        const int n = nBase + wn * 64 + fn * 16 + lr;
        const float bz = (MODE == 1 || MODE == 2) ? bias[n] : 0.0f;
        #pragma unroll
        for (int fm = 0; fm < 8; fm++) {
            #pragma unroll
            for (int r = 0; r < 4; r++) {
                const int m = mBase + wm * 128 + fm * 16 + lq * 4 + r;
                float v = acc[fm][fn][r];
                if (MODE == 0) {
                    v = hs_f(v + pmat[(size_t)(m >> 6) * N + n]) * (float)extra[(size_t)m * N + n];
                } else if (MODE == 1) {
                    v = fmaxf(rowscale[m] * v + bz, 0.0f);
                } else if (MODE == 2) {
                    v = v + bz + (float)extra[(size_t)m * N + n];
                }
                Cmat[(size_t)m * N + n] = (OT)v;
            }
        }
    }
}

// ---------------------------------------------------------------------------
extern "C" void kernel_launch(void* const* d_in, const int* in_sizes, int n_in,
                              void* d_out, int out_size, void* d_ws, size_t ws_size,
                              hipStream_t stream) {
    const float* x   = (const float*)d_in[0];
    const float* n1w = (const float*)d_in[1];
    const float* w1  = (const float*)d_in[2];
    const float* b1  = (const float*)d_in[3];
    const float* n2w = (const float*)d_in[4];
    const float* w2a = (const float*)d_in[5];
    const float* b2a = (const float*)d_in[6];
    const float* w2b = (const float*)d_in[7];
    const float* b2b = (const float*)d_in[8];
    float* y = (float*)d_out;

    char* w = (char*)d_ws;
    float*  inv1  = (float*)(w + 0);
    float*  inv2  = (float*)(w + 65536);
    float*  csum  = (float*)(w + 131072);
    bf16_t* hilo  = (bf16_t*)(w + 1179648);
    float*  Pmat  = (float*)(w + 2228224);
    bf16_t* W1cat = (bf16_t*)(w + 5373952);
    bf16_t* W2at  = (bf16_t*)(w + 9568256);
    bf16_t* W2bt  = (bf16_t*)(w + 17956864);
    bf16_t* outb  = (bf16_t*)(w + 26345472);
    bf16_t* state = (bf16_t*)(w + 59899904);
    bf16_t* hbuf  = state;

    rms_rows_f32<<<dim3(BT_ / 4), dim3(256), 0, stream>>>(x, inv1);
    scan_emit_local<<<dim3(B_ * NCH_, C_ / 256), dim3(256), 0, stream>>>(x, inv1, n1w, state, csum);
    scan_offsets_hilo<<<dim3(B_ * C_ / 256), dim3(256), 0, stream>>>(csum, hilo);
    transpose_scale<<<dim3(C_ / 32, C_ / 32), dim3(256), 0, stream>>>(
        w1, W1cat, C_, C_, 2048, 1024, nullptr);
    transpose_scale<<<dim3(H_ / 32, C_ / 32), dim3(256), 0, stream>>>(
        w2a, W2at, C_, H_, C_, 0, n2w);
    transpose_scale<<<dim3(C_ / 32, H_ / 32), dim3(256), 0, stream>>>(
        w2b, W2bt, H_, C_, H_, 0, nullptr);
    pmat_init<<<dim3(256 * C_ / 256), dim3(256), 0, stream>>>(b1, Pmat);
    gemm_pk<<<dim3(2, C_ / 128, 4), dim3(256), 0, stream>>>(
        hilo, W1cat, Pmat, C_, 512, 2048, 2048);
    // GEMM1: M=16384, N=1024, K=1024 -> grid 64x4 = 256 blocks
    gemm256<0, float, bf16_t><<<dim3(BT_ / 256, C_ / 256), dim3(512), 0, stream>>>(
        state, W1cat, nullptr, x, nullptr, Pmat, outb, C_, C_, C_, 2048);
    rms_rows_bf16<<<dim3(BT_ / 4), dim3(256), 0, stream>>>(outb, inv2);
    for (int c = 0; c < BT_ / MCHUNK; c++) {
        const bf16_t* Ao = outb + (size_t)c * MCHUNK * C_;
        float* yo = y + (size_t)c * MCHUNK * C_;
        // GEMM2a: M=8192, N=4096, K=1024 -> 32x16 = 512 blocks
        gemm256<1, float, bf16_t><<<dim3(MCHUNK / 256, H_ / 256), dim3(512), 0, stream>>>(
            Ao, W2at, b2a, nullptr, inv2 + c * MCHUNK, nullptr, hbuf, H_, C_, C_, C_);
        // GEMM2b: M=8192, N=1024, K=4096 -> 32x4 = 128 blocks
        gemm256<2, bf16_t, float><<<dim3(MCHUNK / 256, C_ / 256), dim3(512), 0, stream>>>(
            hbuf, W2bt, b2b, Ao, nullptr, nullptr, yo, C_, H_, H_, H_);
    }
}

// Round 6
// 738.752 us; speedup vs baseline: 1.0670x; 1.0670x over previous
//
#include <hip/hip_runtime.h>

#define B_     4
#define T_     4096
#define C_     1024
#define H_     4096
#define BT_    (B_ * T_)
#define NCH_   64
#define CHLEN_ 64
#define MCHUNK 8192   // rows per h-chunk for GEMM2a/2b (2 chunks)

typedef __bf16 bf16_t;
typedef __bf16 bf16x8 __attribute__((ext_vector_type(8)));
typedef float  f32x4  __attribute__((ext_vector_type(4)));

__device__ __forceinline__ float hs_f(float v) {
    return fminf(fmaxf((v + 3.0f) * (1.0f / 6.0f), 0.0f), 1.0f) - 0.5f;
}

__device__ __forceinline__ void gld_lds16(const bf16_t* g, bf16_t* l) {
    __builtin_amdgcn_global_load_lds((const __attribute__((address_space(1))) void*)g,
                                     (__attribute__((address_space(3))) void*)l,
                                     16, 0, 0);
}

// ---------------------------------------------------------------------------
__global__ __launch_bounds__(256) void rms_rows_f32(const float* __restrict__ X,
                                                    float* __restrict__ inv) {
    const int wave = threadIdx.x >> 6, lane = threadIdx.x & 63;
    const int row = blockIdx.x * 4 + wave;
    const float* xr = X + (size_t)row * C_;
    float s = 0.0f;
    #pragma unroll
    for (int p = 0; p < 4; p++) {
        float4 v = *(const float4*)(xr + p * 256 + lane * 4);
        s += v.x * v.x + v.y * v.y + v.z * v.z + v.w * v.w;
    }
    #pragma unroll
    for (int o = 32; o > 0; o >>= 1) s += __shfl_down(s, o, 64);
    if (lane == 0) inv[row] = rsqrtf(s * (1.0f / C_) + 1e-6f);
}

__global__ __launch_bounds__(256) void rms_rows_bf16(const bf16_t* __restrict__ X,
                                                     float* __restrict__ inv) {
    const int wave = threadIdx.x >> 6, lane = threadIdx.x & 63;
    const int row = blockIdx.x * 4 + wave;
    const bf16_t* xr = X + (size_t)row * C_;
    bf16x8 v0 = *(const bf16x8*)(xr + lane * 8);
    bf16x8 v1 = *(const bf16x8*)(xr + 512 + lane * 8);
    float s = 0.0f;
    #pragma unroll
    for (int j = 0; j < 8; j++) {
        float a = (float)v0[j], b = (float)v1[j];
        s += a * a + b * b;
    }
    #pragma unroll
    for (int o = 32; o > 0; o >>= 1) s += __shfl_down(s, o, 64);
    if (lane == 0) inv[row] = rsqrtf(s * (1.0f / C_) + 1e-6f);
}

// ---------------------------------------------------------------------------
__global__ __launch_bounds__(256) void scan_emit_local(const float* __restrict__ X,
                                                       const float* __restrict__ inv1,
                                                       const float* __restrict__ nw,
                                                       bf16_t* __restrict__ state,
                                                       float* __restrict__ csum) {
    const int bch = blockIdx.x;
    const int b = bch >> 6, ch = bch & 63;
    const int c = blockIdx.y * 256 + threadIdx.x;
    const float wgt = nw[c];
    const int rbase = b * T_ + ch * CHLEN_;
    const size_t xbase = (size_t)rbase * C_ + c;
    float acc = 0.0f;
    for (int i = 0; i < CHLEN_; i++) {
        acc += hs_f(X[xbase + (size_t)i * C_] * inv1[rbase + i] * wgt);
        state[(size_t)(rbase + i) * C_ + c] = (bf16_t)acc;
    }
    csum[(size_t)bch * C_ + c] = acc;
}

__global__ __launch_bounds__(256) void scan_offsets_hilo(const float* __restrict__ csum,
                                                         bf16_t* __restrict__ hilo) {
    const int idx = blockIdx.x * 256 + threadIdx.x;   // b*1024 + c
    const int b = idx >> 10, c = idx & 1023;
    const size_t base = (size_t)b * NCH_ * C_ + c;
    float v[NCH_];
    #pragma unroll
    for (int ch = 0; ch < NCH_; ch++)
        v[ch] = csum[base + (size_t)ch * C_];
    float run = 0.0f;
    #pragma unroll
    for (int ch = 0; ch < NCH_; ch++) {
        const size_t row = (size_t)(b * NCH_ + ch) * 2048 + c;
        const bf16_t hi = (bf16_t)run;
        hilo[row] = hi;
        hilo[row + 1024] = (bf16_t)(run - (float)hi);
        run += v[ch];
    }
}

__global__ __launch_bounds__(256) void pmat_init(const float* __restrict__ b1,
                                                 float* __restrict__ Pmat) {
    const int i = blockIdx.x * 256 + threadIdx.x;
    Pmat[i] = b1[i & (C_ - 1)];
}

// y = b2b[n] + (f32)outb  (seed for split-K GEMM2b atomics). 8 elems/thread.
__global__ __launch_bounds__(256) void init_y(const float* __restrict__ b2b,
                                              const bf16_t* __restrict__ outb,
                                              float* __restrict__ y) {
    const size_t i = ((size_t)blockIdx.x * 256 + threadIdx.x) * 8;
    bf16x8 o = *(const bf16x8*)(outb + i);
    const int n0 = (int)(i & (C_ - 1));
    #pragma unroll
    for (int j = 0; j < 8; j++)
        y[i + j] = b2b[n0 + j] + (float)o[j];
}

// ---------------------------------------------------------------------------
__global__ __launch_bounds__(256) void transpose_scale(const float* __restrict__ src,
                                                       bf16_t* __restrict__ dst,
                                                       int K, int N, int ldd, int dupOff,
                                                       const float* __restrict__ scale) {
    __shared__ float tile[32][33];
    const int n0 = blockIdx.x * 32, k0 = blockIdx.y * 32;
    const int tx = threadIdx.x & 31, ty = threadIdx.x >> 5;
    #pragma unroll
    for (int j = 0; j < 4; j++) {
        const int kk = ty + j * 8;
        float v = src[(size_t)(k0 + kk) * N + n0 + tx];
        if (scale) v *= scale[k0 + kk];
        tile[kk][tx] = v;
    }
    __syncthreads();
    #pragma unroll
    for (int j = 0; j < 4; j++) {
        const int nn = ty + j * 8;
        const bf16_t v = (bf16_t)tile[tx][nn];
        dst[(size_t)(n0 + nn) * ldd + k0 + tx] = v;
        if (dupOff) dst[(size_t)(n0 + nn) * ldd + dupOff + k0 + tx] = v;
    }
}

// ---------------------------------------------------------------------------
// 128x128 2-barrier GEMM (R3-verified). ~2.6 blocks/CU gives cross-block
// overlap -> the right structure for SHORT-K GEMMs (K=1024: 8-phase's
// prologue/epilogue don't amortize, R5 post-mortem).
// MODE 1: out bf16 = relu(rowscale[m]*acc + bias[n])   (GEMM2a)
// MODE 4: atomicAdd(out f32, acc)                      (split-K P-GEMM)
// ---------------------------------------------------------------------------
template <int MODE, typename OT>
__global__ __launch_bounds__(256) void gemm_bt(const bf16_t* __restrict__ A,
                                               const bf16_t* __restrict__ Bt,
                                               const float* __restrict__ bias,
                                               const float* __restrict__ rowscale,
                                               OT* __restrict__ Cmat,
                                               int N, int K, int lda, int ldb) {
    __shared__ __align__(16) bf16_t As[128 * 32];
    __shared__ __align__(16) bf16_t Bs[128 * 32];
    const int tid = threadIdx.x;

    const int nwgx = gridDim.x;
    const int flat0 = blockIdx.y * nwgx + blockIdx.x;
    int mTile, nTile;
    if ((nwgx & 7) == 0) {                  // XCD m-slice mapping (R3 win)
        const int xcd = flat0 & 7;
        const int loc = flat0 >> 3;
        const int mpx = nwgx >> 3;
        mTile = xcd * mpx + (loc % mpx);
        nTile = loc / mpx;
    } else {
        mTile = blockIdx.x;
        nTile = blockIdx.y;
    }
    const int mBase = mTile * 128;
    const int nBase = nTile * 128;
    const size_t kOff = (size_t)blockIdx.z * K;

    const int wave = tid >> 6;
    const int lane = tid & 63;
    const int waveM = (wave & 1) * 64;
    const int waveN = (wave >> 1) * 64;
    const int lr = lane & 15;
    const int lq = lane >> 4;

    f32x4 acc[4][4] = {};

    const int e0 = tid * 8;
    const int r0 = e0 >> 5, c0 = e0 & 31;
    const int e1 = 2048 + tid * 8;
    const int r1 = e1 >> 5, c1 = e1 & 31;

    const bf16_t* Ag0 = A + (size_t)(mBase + r0) * lda + kOff + c0;
    const bf16_t* Ag1 = A + (size_t)(mBase + r1) * lda + kOff + c1;
    const bf16_t* Bg0 = Bt + (size_t)(nBase + r0) * ldb + kOff + c0;
    const bf16_t* Bg1 = Bt + (size_t)(nBase + r1) * ldb + kOff + c1;

    for (int kb = 0; kb < K; kb += 32) {
        __syncthreads();
        gld_lds16(Ag0 + kb, As + e0);
        gld_lds16(Ag1 + kb, As + e1);
        gld_lds16(Bg0 + kb, Bs + e0);
        gld_lds16(Bg1 + kb, Bs + e1);
        __syncthreads();

        bf16x8 af[4], bfr[4];
        #pragma unroll
        for (int mi = 0; mi < 4; mi++)
            af[mi] = *(const bf16x8*)(As + (waveM + mi * 16 + lr) * 32 + lq * 8);
        #pragma unroll
        for (int ni = 0; ni < 4; ni++)
            bfr[ni] = *(const bf16x8*)(Bs + (waveN + ni * 16 + lr) * 32 + lq * 8);
        #pragma unroll
        for (int mi = 0; mi < 4; mi++)
            #pragma unroll
            for (int ni = 0; ni < 4; ni++)
                acc[mi][ni] = __builtin_amdgcn_mfma_f32_16x16x32_bf16(
                    af[mi], bfr[ni], acc[mi][ni], 0, 0, 0);
    }

    #pragma unroll
    for (int ni = 0; ni < 4; ni++) {
        const int n = nBase + waveN + ni * 16 + lr;
        const float bz = (MODE == 1) ? bias[n] : 0.0f;
        #pragma unroll
        for (int mi = 0; mi < 4; mi++) {
            #pragma unroll
            for (int r = 0; r < 4; r++) {
                const int m = mBase + waveM + mi * 16 + lq * 4 + r;
                float v = acc[mi][ni][r];
                if (MODE == 1) {
                    v = fmaxf(rowscale[m] * v + bz, 0.0f);
                    Cmat[(size_t)m * N + n] = (OT)v;
                } else {
                    atomicAdd((float*)&Cmat[(size_t)m * N + n], v);
                }
            }
        }
    }
}

// ---------------------------------------------------------------------------
// 256x256 8-phase bf16 GEMM (R5 schedule, verified correct; bank-conflict 0).
// For LONG-K / full-grid GEMMs only. + blockIdx.z K-slice (additive offset).
// MODE 0: out bf16 = hs(acc + pmat[(m>>6)*N+n]) * xf32[m*N+n]   (GEMM1)
// MODE 5: atomicAdd(out f32, acc)                     (split-K GEMM2b)
// ---------------------------------------------------------------------------
template <int MODE, typename ET, typename OT>
__global__ __launch_bounds__(512, 2) void gemm256(const bf16_t* __restrict__ A,
                                                  const bf16_t* __restrict__ Bt,
                                                  const ET* __restrict__ extra,
                                                  const float* __restrict__ pmat,
                                                  OT* __restrict__ Cmat,
                                                  int N, int K, int lda, int ldb) {
    __shared__ __align__(16) bf16_t lds[2][2][256 * 64];   // 128 KiB

    const int tid = threadIdx.x;
    const int wave = tid >> 6, lane = tid & 63;
    const int wm = wave >> 2;
    const int wn = wave & 3;
    const int lr = lane & 15;
    const int lq = lane >> 4;

    const int nwgx = gridDim.x;
    const int flat0 = blockIdx.y * nwgx + blockIdx.x;
    int mTile, nTile;
    if ((nwgx & 7) == 0) {
        const int xcd = flat0 & 7;
        const int loc = flat0 >> 3;
        const int mpx = nwgx >> 3;
        mTile = xcd * mpx + (loc % mpx);
        nTile = loc / mpx;
    } else {
        mTile = blockIdx.x;
        nTile = blockIdx.y;
    }
    const int mBase = mTile * 256;
    const int nBase = nTile * 256;
    const size_t kOff = (size_t)blockIdx.z * K;   // split-K slice

    const bf16_t* Abase = A + (size_t)mBase * lda + kOff;
    const bf16_t* Bbase = Bt + (size_t)nBase * ldb + kOff;

    auto stage = [&](int buf, int arr, int odd, int kb) {
        #pragma unroll
        for (int j = 0; j < 2; j++) {
            const int ps = tid + (j << 9);
            const int s  = ps & 7;
            const int q  = ps >> 3;
            int row;
            if (arr == 0) row = ((q >> 6) << 7) | (odd << 6) | (q & 63);
            else          row = ((q >> 5) << 6) | (odd << 5) | (q & 31);
            const int c = (s ^ (row & 7)) << 3;
            const bf16_t* src = (arr == 0 ? Abase + (size_t)row * lda
                                          : Bbase + (size_t)row * ldb) + kb + c;
            gld_lds16(src, &lds[buf][arr][row * 64 + s * 8]);
        }
    };

    f32x4 acc[8][4] = {};

    stage(0, 0, 0, 0); stage(0, 1, 0, 0); stage(0, 0, 1, 0); stage(0, 1, 1, 0);
    stage(1, 0, 0, 64); stage(1, 1, 0, 64);
    asm volatile("s_waitcnt vmcnt(4)" ::: "memory");
    __builtin_amdgcn_s_barrier();

    const int NIT = K >> 7;
    for (int it = 0; it < NIT; ++it) {
        const bool nl = (it + 1 < NIT);
        const int k1 = ((it << 1) + 1) << 6;
        const int k2 = ((it << 1) + 2) << 6;
        const int k3 = ((it << 1) + 3) << 6;

        #pragma unroll
        for (int p = 0; p < 8; ++p) {
            const int buf = p >> 2;
            const int mh = (p >> 1) & 1, nh = p & 1;
            const bf16_t* At = &lds[buf][0][0];
            const bf16_t* Bl = &lds[buf][1][0];

            bf16x8 af[4][2], bfr[2][2];
            #pragma unroll
            for (int mi = 0; mi < 4; mi++) {
                const int R = wm * 128 + mh * 64 + mi * 16 + lr;
                const size_t rb = (size_t)R * 64;
                #pragma unroll
                for (int ks = 0; ks < 2; ks++)
                    af[mi][ks] = *(const bf16x8*)(At + rb + ((((ks << 2) | lq) ^ (R & 7)) << 3));
            }
            #pragma unroll
            for (int ni = 0; ni < 2; ni++) {
                const int R = wn * 64 + nh * 32 + ni * 16 + lr;
                const size_t rb = (size_t)R * 64;
                #pragma unroll
                for (int ks = 0; ks < 2; ks++)
                    bfr[ni][ks] = *(const bf16x8*)(Bl + rb + ((((ks << 2) | lq) ^ (R & 7)) << 3));
            }

            switch (p) {
                case 0: stage(1, 0, 1, k1); break;
                case 1: stage(1, 1, 1, k1); break;
                case 2: if (nl) stage(0, 0, 0, k2); break;
                case 3: if (nl) stage(0, 1, 0, k2); break;
                case 4: if (nl) stage(0, 0, 1, k2); break;
                case 5: if (nl) stage(0, 1, 1, k2); break;
                case 6: if (nl) stage(1, 0, 0, k3); break;
                case 7: if (nl) stage(1, 1, 0, k3); break;
            }
            if (p == 3) {
                if (nl) asm volatile("s_waitcnt vmcnt(4)" ::: "memory");
                else    asm volatile("s_waitcnt vmcnt(0)" ::: "memory");
            }
            if (p == 7 && nl) asm volatile("s_waitcnt vmcnt(4)" ::: "memory");

            __builtin_amdgcn_s_barrier();
            __builtin_amdgcn_s_setprio(1);
            #pragma unroll
            for (int mi = 0; mi < 4; mi++)
                #pragma unroll
                for (int ni = 0; ni < 2; ni++) {
                    acc[mh * 4 + mi][nh * 2 + ni] = __builtin_amdgcn_mfma_f32_16x16x32_bf16(
                        af[mi][0], bfr[ni][0], acc[mh * 4 + mi][nh * 2 + ni], 0, 0, 0);
                    acc[mh * 4 + mi][nh * 2 + ni] = __builtin_amdgcn_mfma_f32_16x16x32_bf16(
                        af[mi][1], bfr[ni][1], acc[mh * 4 + mi][nh * 2 + ni], 0, 0, 0);
                }
            __builtin_amdgcn_s_setprio(0);
            __builtin_amdgcn_s_barrier();
        }
    }

    #pragma unroll
    for (int fn = 0; fn < 4; fn++) {
        const int n = nBase + wn * 64 + fn * 16 + lr;
        #pragma unroll
        for (int fm = 0; fm < 8; fm++) {
            #pragma unroll
            for (int r = 0; r < 4; r++) {
                const int m = mBase + wm * 128 + fm * 16 + lq * 4 + r;
                float v = acc[fm][fn][r];
                if (MODE == 0) {
                    v = hs_f(v + pmat[(size_t)(m >> 6) * N + n]) * (float)extra[(size_t)m * N + n];
                    Cmat[(size_t)m * N + n] = (OT)v;
                } else {
                    atomicAdd((float*)&Cmat[(size_t)m * N + n], v);
                }
            }
        }
    }
}

// ---------------------------------------------------------------------------
extern "C" void kernel_launch(void* const* d_in, const int* in_sizes, int n_in,
                              void* d_out, int out_size, void* d_ws, size_t ws_size,
                              hipStream_t stream) {
    const float* x   = (const float*)d_in[0];
    const float* n1w = (const float*)d_in[1];
    const float* w1  = (const float*)d_in[2];
    const float* b1  = (const float*)d_in[3];
    const float* n2w = (const float*)d_in[4];
    const float* w2a = (const float*)d_in[5];
    const float* b2a = (const float*)d_in[6];
    const float* w2b = (const float*)d_in[7];
    const float* b2b = (const float*)d_in[8];
    float* y = (float*)d_out;

    char* w = (char*)d_ws;
    float*  inv1  = (float*)(w + 0);
    float*  inv2  = (float*)(w + 65536);
    float*  csum  = (float*)(w + 131072);
    bf16_t* hilo  = (bf16_t*)(w + 1179648);
    float*  Pmat  = (float*)(w + 2228224);
    bf16_t* W1cat = (bf16_t*)(w + 5373952);
    bf16_t* W2at  = (bf16_t*)(w + 9568256);
    bf16_t* W2bt  = (bf16_t*)(w + 17956864);
    bf16_t* outb  = (bf16_t*)(w + 26345472);
    bf16_t* state = (bf16_t*)(w + 59899904);
    bf16_t* hbuf  = state;

    rms_rows_f32<<<dim3(BT_ / 4), dim3(256), 0, stream>>>(x, inv1);
    scan_emit_local<<<dim3(B_ * NCH_, C_ / 256), dim3(256), 0, stream>>>(x, inv1, n1w, state, csum);
    scan_offsets_hilo<<<dim3(B_ * C_ / 256), dim3(256), 0, stream>>>(csum, hilo);
    transpose_scale<<<dim3(C_ / 32, C_ / 32), dim3(256), 0, stream>>>(
        w1, W1cat, C_, C_, 2048, 1024, nullptr);
    transpose_scale<<<dim3(H_ / 32, C_ / 32), dim3(256), 0, stream>>>(
        w2a, W2at, C_, H_, C_, 0, n2w);
    transpose_scale<<<dim3(C_ / 32, H_ / 32), dim3(256), 0, stream>>>(
        w2b, W2bt, H_, C_, H_, 0, nullptr);
    pmat_init<<<dim3(256 * C_ / 256), dim3(256), 0, stream>>>(b1, Pmat);
    gemm_bt<4, float><<<dim3(2, C_ / 128, 4), dim3(256), 0, stream>>>(
        hilo, W1cat, nullptr, nullptr, Pmat, C_, 512, 2048, 2048);
    // GEMM1: M=16384, N=1024, K=1024 -> 64x4 = 256 blocks (8-phase, 1 round)
    gemm256<0, float, bf16_t><<<dim3(BT_ / 256, C_ / 256), dim3(512), 0, stream>>>(
        state, W1cat, x, Pmat, outb, C_, C_, C_, 2048);
    rms_rows_bf16<<<dim3(BT_ / 4), dim3(256), 0, stream>>>(outb, inv2);
    // y seed: b2b + outb (split-K GEMM2b accumulates on top)
    init_y<<<dim3(BT_ * C_ / (256 * 8)), dim3(256), 0, stream>>>(b2b, outb, y);
    for (int c = 0; c < BT_ / MCHUNK; c++) {
        const bf16_t* Ao = outb + (size_t)c * MCHUNK * C_;
        float* yo = y + (size_t)c * MCHUNK * C_;
        // GEMM2a: short K=1024 -> 2-barrier 128x128, 64x32 = 2048 blocks
        gemm_bt<1, bf16_t><<<dim3(MCHUNK / 128, H_ / 128), dim3(256), 0, stream>>>(
            Ao, W2at, b2a, inv2 + c * MCHUNK, hbuf, H_, C_, C_, C_);
        // GEMM2b: long K=4096 -> 8-phase 256x256, split-K x2: (32,4,2) = 256 blocks
        gemm256<5, float, float><<<dim3(MCHUNK / 256, C_ / 256, 2), dim3(512), 0, stream>>>(
            hbuf, W2bt, nullptr, nullptr, yo, C_, H_ / 2, H_, H_);
    }
}

// Round 7
// 708.998 us; speedup vs baseline: 1.1118x; 1.0420x over previous
//
#include <hip/hip_runtime.h>

#define B_     4
#define T_     4096
#define C_     1024
#define H_     4096
#define BT_    (B_ * T_)
#define NCH_   64
#define CHLEN_ 64
#define MCHUNK 8192   // rows per h-chunk for GEMM2a/2b (2 chunks)

typedef __bf16 bf16_t;
typedef __bf16 bf16x8 __attribute__((ext_vector_type(8)));
typedef float  f32x4  __attribute__((ext_vector_type(4)));

__device__ __forceinline__ float hs_f(float v) {
    return fminf(fmaxf((v + 3.0f) * (1.0f / 6.0f), 0.0f), 1.0f) - 0.5f;
}

__device__ __forceinline__ void gld_lds16(const bf16_t* g, bf16_t* l) {
    __builtin_amdgcn_global_load_lds((const __attribute__((address_space(1))) void*)g,
                                     (__attribute__((address_space(3))) void*)l,
                                     16, 0, 0);
}

// ---------------------------------------------------------------------------
__global__ __launch_bounds__(256) void rms_rows_f32(const float* __restrict__ X,
                                                    float* __restrict__ inv) {
    const int wave = threadIdx.x >> 6, lane = threadIdx.x & 63;
    const int row = blockIdx.x * 4 + wave;
    const float* xr = X + (size_t)row * C_;
    float s = 0.0f;
    #pragma unroll
    for (int p = 0; p < 4; p++) {
        float4 v = *(const float4*)(xr + p * 256 + lane * 4);
        s += v.x * v.x + v.y * v.y + v.z * v.z + v.w * v.w;
    }
    #pragma unroll
    for (int o = 32; o > 0; o >>= 1) s += __shfl_down(s, o, 64);
    if (lane == 0) inv[row] = rsqrtf(s * (1.0f / C_) + 1e-6f);
}

__global__ __launch_bounds__(256) void rms_rows_bf16(const bf16_t* __restrict__ X,
                                                     float* __restrict__ inv) {
    const int wave = threadIdx.x >> 6, lane = threadIdx.x & 63;
    const int row = blockIdx.x * 4 + wave;
    const bf16_t* xr = X + (size_t)row * C_;
    bf16x8 v0 = *(const bf16x8*)(xr + lane * 8);
    bf16x8 v1 = *(const bf16x8*)(xr + 512 + lane * 8);
    float s = 0.0f;
    #pragma unroll
    for (int j = 0; j < 8; j++) {
        float a = (float)v0[j], b = (float)v1[j];
        s += a * a + b * b;
    }
    #pragma unroll
    for (int o = 32; o > 0; o >>= 1) s += __shfl_down(s, o, 64);
    if (lane == 0) inv[row] = rsqrtf(s * (1.0f / C_) + 1e-6f);
}

// ---------------------------------------------------------------------------
__global__ __launch_bounds__(256) void scan_emit_local(const float* __restrict__ X,
                                                       const float* __restrict__ inv1,
                                                       const float* __restrict__ nw,
                                                       bf16_t* __restrict__ state,
                                                       float* __restrict__ csum) {
    const int bch = blockIdx.x;
    const int b = bch >> 6, ch = bch & 63;
    const int c = blockIdx.y * 256 + threadIdx.x;
    const float wgt = nw[c];
    const int rbase = b * T_ + ch * CHLEN_;
    const size_t xbase = (size_t)rbase * C_ + c;
    float acc = 0.0f;
    for (int i = 0; i < CHLEN_; i++) {
        acc += hs_f(X[xbase + (size_t)i * C_] * inv1[rbase + i] * wgt);
        state[(size_t)(rbase + i) * C_ + c] = (bf16_t)acc;
    }
    csum[(size_t)bch * C_ + c] = acc;
}

__global__ __launch_bounds__(256) void scan_offsets_hilo(const float* __restrict__ csum,
                                                         bf16_t* __restrict__ hilo) {
    const int idx = blockIdx.x * 256 + threadIdx.x;   // b*1024 + c
    const int b = idx >> 10, c = idx & 1023;
    const size_t base = (size_t)b * NCH_ * C_ + c;
    float v[NCH_];
    #pragma unroll
    for (int ch = 0; ch < NCH_; ch++)
        v[ch] = csum[base + (size_t)ch * C_];
    float run = 0.0f;
    #pragma unroll
    for (int ch = 0; ch < NCH_; ch++) {
        const size_t row = (size_t)(b * NCH_ + ch) * 2048 + c;
        const bf16_t hi = (bf16_t)run;
        hilo[row] = hi;
        hilo[row + 1024] = (bf16_t)(run - (float)hi);
        run += v[ch];
    }
}

__global__ __launch_bounds__(256) void pmat_init(const float* __restrict__ b1,
                                                 float* __restrict__ Pmat) {
    const int i = blockIdx.x * 256 + threadIdx.x;
    Pmat[i] = b1[i & (C_ - 1)];
}

// y = b2b[n] + (f32)outb  (seed for split-K GEMM2b atomics). 8 elems/thread.
__global__ __launch_bounds__(256) void init_y(const float* __restrict__ b2b,
                                              const bf16_t* __restrict__ outb,
                                              float* __restrict__ y) {
    const size_t i = ((size_t)blockIdx.x * 256 + threadIdx.x) * 8;
    bf16x8 o = *(const bf16x8*)(outb + i);
    const int n0 = (int)(i & (C_ - 1));
    #pragma unroll
    for (int j = 0; j < 8; j++)
        y[i + j] = b2b[n0 + j] + (float)o[j];
}

// ---------------------------------------------------------------------------
__global__ __launch_bounds__(256) void transpose_scale(const float* __restrict__ src,
                                                       bf16_t* __restrict__ dst,
                                                       int K, int N, int ldd, int dupOff,
                                                       const float* __restrict__ scale) {
    __shared__ float tile[32][33];
    const int n0 = blockIdx.x * 32, k0 = blockIdx.y * 32;
    const int tx = threadIdx.x & 31, ty = threadIdx.x >> 5;
    #pragma unroll
    for (int j = 0; j < 4; j++) {
        const int kk = ty + j * 8;
        float v = src[(size_t)(k0 + kk) * N + n0 + tx];
        if (scale) v *= scale[k0 + kk];
        tile[kk][tx] = v;
    }
    __syncthreads();
    #pragma unroll
    for (int j = 0; j < 4; j++) {
        const int nn = ty + j * 8;
        const bf16_t v = (bf16_t)tile[tx][nn];
        dst[(size_t)(n0 + nn) * ldd + k0 + tx] = v;
        if (dupOff) dst[(size_t)(n0 + nn) * ldd + dupOff + k0 + tx] = v;
    }
}

// ---------------------------------------------------------------------------
// 128x128 GEMM, 2-PHASE double-buffered (R6 rework of the 2-barrier kernel):
//   prologue: STAGE(buf0,k=0); __syncthreads()
//   iter:     STAGE(buf^1,k+32) -> ds_read+MFMA(buf) -> __syncthreads(); swap
// Staging overlaps compute (T3 minimal recipe); one drain+barrier per tile.
// LDS 2x16KB = 32 KiB -> 5 blocks/CU (cross-block overlap retained).
//
// LDS swizzle (T2, R6): [128][32]bf16 rows = 64B = 4x16B slots; unswizzled, a
// 16-lane ds_read_b128 column hits 2 bank-quads = 8-way conflict (R6 PMC:
// 8.4M). Phys slot s' = s ^ ((row>>1)&3) -> all 8 quads, 2-way = free.
// Rule #21: LDS dest linear (gld_lds needs uniform+lane*16), GLOBAL source
// col carries the XOR, ds_read applies the same XOR. Bitwise-same numerics.
//
// MODE 0: out bf16 = hs(acc + pmat[(m>>6)*N+n]) * xf32[m*N+n]   (GEMM1)
// MODE 1: out bf16 = relu(rowscale[m]*acc + bias[n])            (GEMM2a)
// MODE 4: atomicAdd(out f32, acc)                               (split-K P-GEMM)
// ---------------------------------------------------------------------------
template <int MODE, typename ET, typename OT>
__global__ __launch_bounds__(256) void gemm_bt(const bf16_t* __restrict__ A,
                                               const bf16_t* __restrict__ Bt,
                                               const float* __restrict__ bias,
                                               const ET* __restrict__ extra,
                                               const float* __restrict__ rowscale,
                                               const float* __restrict__ pmat,
                                               OT* __restrict__ Cmat,
                                               int N, int K, int lda, int ldb) {
    __shared__ __align__(16) bf16_t As[2][128 * 32];
    __shared__ __align__(16) bf16_t Bs[2][128 * 32];
    const int tid = threadIdx.x;

    const int nwgx = gridDim.x;
    const int flat0 = blockIdx.y * nwgx + blockIdx.x;
    int mTile, nTile;
    if ((nwgx & 7) == 0) {                  // XCD m-slice mapping (R3 win)
        const int xcd = flat0 & 7;
        const int loc = flat0 >> 3;
        const int mpx = nwgx >> 3;
        mTile = xcd * mpx + (loc % mpx);
        nTile = loc / mpx;
    } else {
        mTile = blockIdx.x;
        nTile = blockIdx.y;
    }
    const int mBase = mTile * 128;
    const int nBase = nTile * 128;
    const size_t kOff = (size_t)blockIdx.z * K;

    const int wave = tid >> 6;
    const int lane = tid & 63;
    const int waveM = (wave & 1) * 64;
    const int waveN = (wave >> 1) * 64;
    const int lr = lane & 15;
    const int lq = lane >> 4;

    f32x4 acc[4][4] = {};

    // Staging: thread covers elements e0=tid*8 and e1=2048+tid*8 (LDS linear,
    // wave-uniform + lane*16). Source col pre-swizzled: logical slot for phys
    // slot sp at row r is sp ^ ((r>>1)&3).
    const int e0 = tid * 8;
    const int r0 = e0 >> 5, c0 = (((e0 >> 3) & 3) ^ ((r0 >> 1) & 3)) << 3;
    const int e1 = 2048 + tid * 8;
    const int r1 = e1 >> 5, c1 = (((e1 >> 3) & 3) ^ ((r1 >> 1) & 3)) << 3;

    const bf16_t* Ag0 = A + (size_t)(mBase + r0) * lda + kOff + c0;
    const bf16_t* Ag1 = A + (size_t)(mBase + r1) * lda + kOff + c1;
    const bf16_t* Bg0 = Bt + (size_t)(nBase + r0) * ldb + kOff + c0;
    const bf16_t* Bg1 = Bt + (size_t)(nBase + r1) * ldb + kOff + c1;

    auto stage = [&](int buf, int kb) {
        gld_lds16(Ag0 + kb, As[buf] + e0);
        gld_lds16(Ag1 + kb, As[buf] + e1);
        gld_lds16(Bg0 + kb, Bs[buf] + e0);
        gld_lds16(Bg1 + kb, Bs[buf] + e1);
    };

    stage(0, 0);
    __syncthreads();                        // vmcnt(0)+lgkmcnt(0)+barrier

    int cur = 0;
    for (int kb = 0; kb < K; kb += 32) {
        if (kb + 32 < K) stage(cur ^ 1, kb + 32);   // overlap next-tile stage

        bf16x8 af[4], bfr[4];
        #pragma unroll
        for (int mi = 0; mi < 4; mi++) {
            const int R = waveM + mi * 16 + lr;
            af[mi] = *(const bf16x8*)(As[cur] + R * 32 + ((lq ^ ((R >> 1) & 3)) << 3));
        }
        #pragma unroll
        for (int ni = 0; ni < 4; ni++) {
            const int R = waveN + ni * 16 + lr;
            bfr[ni] = *(const bf16x8*)(Bs[cur] + R * 32 + ((lq ^ ((R >> 1) & 3)) << 3));
        }
        #pragma unroll
        for (int mi = 0; mi < 4; mi++)
            #pragma unroll
            for (int ni = 0; ni < 4; ni++)
                acc[mi][ni] = __builtin_amdgcn_mfma_f32_16x16x32_bf16(
                    af[mi], bfr[ni], acc[mi][ni], 0, 0, 0);

        __syncthreads();                    // drain staged writes; next iter reads them
        cur ^= 1;
    }

    // Epilogue. C/D layout: col(n)=lane&15, row(m)=(lane>>4)*4+reg.
    #pragma unroll
    for (int ni = 0; ni < 4; ni++) {
        const int n = nBase + waveN + ni * 16 + lr;
        const float bz = (MODE == 1) ? bias[n] : 0.0f;
        #pragma unroll
        for (int mi = 0; mi < 4; mi++) {
            #pragma unroll
            for (int r = 0; r < 4; r++) {
                const int m = mBase + waveM + mi * 16 + lq * 4 + r;
                float v = acc[mi][ni][r];
                if (MODE == 0) {
                    v = hs_f(v + pmat[(size_t)(m >> 6) * N + n]) * (float)extra[(size_t)m * N + n];
                    Cmat[(size_t)m * N + n] = (OT)v;
                } else if (MODE == 1) {
                    v = fmaxf(rowscale[m] * v + bz, 0.0f);
                    Cmat[(size_t)m * N + n] = (OT)v;
                } else {
                    atomicAdd((float*)&Cmat[(size_t)m * N + n], v);
                }
            }
        }
    }
}

// ---------------------------------------------------------------------------
// 256x256 8-phase bf16 GEMM (R5 schedule, verified; bank-conflict 0).
// LONG-K full-grid GEMMs only. blockIdx.z K-slice (additive offset).
// MODE 5: atomicAdd(out f32, acc)   (split-K GEMM2b)
// ---------------------------------------------------------------------------
template <int MODE, typename ET, typename OT>
__global__ __launch_bounds__(512, 2) void gemm256(const bf16_t* __restrict__ A,
                                                  const bf16_t* __restrict__ Bt,
                                                  const ET* __restrict__ extra,
                                                  const float* __restrict__ pmat,
                                                  OT* __restrict__ Cmat,
                                                  int N, int K, int lda, int ldb) {
    __shared__ __align__(16) bf16_t lds[2][2][256 * 64];   // 128 KiB

    const int tid = threadIdx.x;
    const int wave = tid >> 6, lane = tid & 63;
    const int wm = wave >> 2;
    const int wn = wave & 3;
    const int lr = lane & 15;
    const int lq = lane >> 4;

    const int nwgx = gridDim.x;
    const int flat0 = blockIdx.y * nwgx + blockIdx.x;
    int mTile, nTile;
    if ((nwgx & 7) == 0) {
        const int xcd = flat0 & 7;
        const int loc = flat0 >> 3;
        const int mpx = nwgx >> 3;
        mTile = xcd * mpx + (loc % mpx);
        nTile = loc / mpx;
    } else {
        mTile = blockIdx.x;
        nTile = blockIdx.y;
    }
    const int mBase = mTile * 256;
    const int nBase = nTile * 256;
    const size_t kOff = (size_t)blockIdx.z * K;

    const bf16_t* Abase = A + (size_t)mBase * lda + kOff;
    const bf16_t* Bbase = Bt + (size_t)nBase * ldb + kOff;

    auto stage = [&](int buf, int arr, int odd, int kb) {
        #pragma unroll
        for (int j = 0; j < 2; j++) {
            const int ps = tid + (j << 9);
            const int s  = ps & 7;
            const int q  = ps >> 3;
            int row;
            if (arr == 0) row = ((q >> 6) << 7) | (odd << 6) | (q & 63);
            else          row = ((q >> 5) << 6) | (odd << 5) | (q & 31);
            const int c = (s ^ (row & 7)) << 3;
            const bf16_t* src = (arr == 0 ? Abase + (size_t)row * lda
                                          : Bbase + (size_t)row * ldb) + kb + c;
            gld_lds16(src, &lds[buf][arr][row * 64 + s * 8]);
        }
    };

    f32x4 acc[8][4] = {};

    stage(0, 0, 0, 0); stage(0, 1, 0, 0); stage(0, 0, 1, 0); stage(0, 1, 1, 0);
    stage(1, 0, 0, 64); stage(1, 1, 0, 64);
    asm volatile("s_waitcnt vmcnt(4)" ::: "memory");
    __builtin_amdgcn_s_barrier();

    const int NIT = K >> 7;
    for (int it = 0; it < NIT; ++it) {
        const bool nl = (it + 1 < NIT);
        const int k1 = ((it << 1) + 1) << 6;
        const int k2 = ((it << 1) + 2) << 6;
        const int k3 = ((it << 1) + 3) << 6;

        #pragma unroll
        for (int p = 0; p < 8; ++p) {
            const int buf = p >> 2;
            const int mh = (p >> 1) & 1, nh = p & 1;
            const bf16_t* At = &lds[buf][0][0];
            const bf16_t* Bl = &lds[buf][1][0];

            bf16x8 af[4][2], bfr[2][2];
            #pragma unroll
            for (int mi = 0; mi < 4; mi++) {
                const int R = wm * 128 + mh * 64 + mi * 16 + lr;
                const size_t rb = (size_t)R * 64;
                #pragma unroll
                for (int ks = 0; ks < 2; ks++)
                    af[mi][ks] = *(const bf16x8*)(At + rb + ((((ks << 2) | lq) ^ (R & 7)) << 3));
            }
            #pragma unroll
            for (int ni = 0; ni < 2; ni++) {
                const int R = wn * 64 + nh * 32 + ni * 16 + lr;
                const size_t rb = (size_t)R * 64;
                #pragma unroll
                for (int ks = 0; ks < 2; ks++)
                    bfr[ni][ks] = *(const bf16x8*)(Bl + rb + ((((ks << 2) | lq) ^ (R & 7)) << 3));
            }

            switch (p) {
                case 0: stage(1, 0, 1, k1); break;
                case 1: stage(1, 1, 1, k1); break;
                case 2: if (nl) stage(0, 0, 0, k2); break;
                case 3: if (nl) stage(0, 1, 0, k2); break;
                case 4: if (nl) stage(0, 0, 1, k2); break;
                case 5: if (nl) stage(0, 1, 1, k2); break;
                case 6: if (nl) stage(1, 0, 0, k3); break;
                case 7: if (nl) stage(1, 1, 0, k3); break;
            }
            if (p == 3) {
                if (nl) asm volatile("s_waitcnt vmcnt(4)" ::: "memory");
                else    asm volatile("s_waitcnt vmcnt(0)" ::: "memory");
            }
            if (p == 7 && nl) asm volatile("s_waitcnt vmcnt(4)" ::: "memory");

            __builtin_amdgcn_s_barrier();
            __builtin_amdgcn_s_setprio(1);
            #pragma unroll
            for (int mi = 0; mi < 4; mi++)
                #pragma unroll
                for (int ni = 0; ni < 2; ni++) {
                    acc[mh * 4 + mi][nh * 2 + ni] = __builtin_amdgcn_mfma_f32_16x16x32_bf16(
                        af[mi][0], bfr[ni][0], acc[mh * 4 + mi][nh * 2 + ni], 0, 0, 0);
                    acc[mh * 4 + mi][nh * 2 + ni] = __builtin_amdgcn_mfma_f32_16x16x32_bf16(
                        af[mi][1], bfr[ni][1], acc[mh * 4 + mi][nh * 2 + ni], 0, 0, 0);
                }
            __builtin_amdgcn_s_setprio(0);
            __builtin_amdgcn_s_barrier();
        }
    }

    #pragma unroll
    for (int fn = 0; fn < 4; fn++) {
        const int n = nBase + wn * 64 + fn * 16 + lr;
        #pragma unroll
        for (int fm = 0; fm < 8; fm++) {
            #pragma unroll
            for (int r = 0; r < 4; r++) {
                const int m = mBase + wm * 128 + fm * 16 + lq * 4 + r;
                float v = acc[fm][fn][r];
                if (MODE == 0) {
                    v = hs_f(v + pmat[(size_t)(m >> 6) * N + n]) * (float)extra[(size_t)m * N + n];
                    Cmat[(size_t)m * N + n] = (OT)v;
                } else {
                    atomicAdd((float*)&Cmat[(size_t)m * N + n], v);
                }
            }
        }
    }
}

// ---------------------------------------------------------------------------
extern "C" void kernel_launch(void* const* d_in, const int* in_sizes, int n_in,
                              void* d_out, int out_size, void* d_ws, size_t ws_size,
                              hipStream_t stream) {
    const float* x   = (const float*)d_in[0];
    const float* n1w = (const float*)d_in[1];
    const float* w1  = (const float*)d_in[2];
    const float* b1  = (const float*)d_in[3];
    const float* n2w = (const float*)d_in[4];
    const float* w2a = (const float*)d_in[5];
    const float* b2a = (const float*)d_in[6];
    const float* w2b = (const float*)d_in[7];
    const float* b2b = (const float*)d_in[8];
    float* y = (float*)d_out;

    char* w = (char*)d_ws;
    float*  inv1  = (float*)(w + 0);
    float*  inv2  = (float*)(w + 65536);
    float*  csum  = (float*)(w + 131072);
    bf16_t* hilo  = (bf16_t*)(w + 1179648);
    float*  Pmat  = (float*)(w + 2228224);
    bf16_t* W1cat = (bf16_t*)(w + 5373952);
    bf16_t* W2at  = (bf16_t*)(w + 9568256);
    bf16_t* W2bt  = (bf16_t*)(w + 17956864);
    bf16_t* outb  = (bf16_t*)(w + 26345472);
    bf16_t* state = (bf16_t*)(w + 59899904);
    bf16_t* hbuf  = state;

    rms_rows_f32<<<dim3(BT_ / 4), dim3(256), 0, stream>>>(x, inv1);
    scan_emit_local<<<dim3(B_ * NCH_, C_ / 256), dim3(256), 0, stream>>>(x, inv1, n1w, state, csum);
    scan_offsets_hilo<<<dim3(B_ * C_ / 256), dim3(256), 0, stream>>>(csum, hilo);
    transpose_scale<<<dim3(C_ / 32, C_ / 32), dim3(256), 0, stream>>>(
        w1, W1cat, C_, C_, 2048, 1024, nullptr);
    transpose_scale<<<dim3(H_ / 32, C_ / 32), dim3(256), 0, stream>>>(
        w2a, W2at, C_, H_, C_, 0, n2w);
    transpose_scale<<<dim3(C_ / 32, H_ / 32), dim3(256), 0, stream>>>(
        w2b, W2bt, H_, C_, H_, 0, nullptr);
    pmat_init<<<dim3(256 * C_ / 256), dim3(256), 0, stream>>>(b1, Pmat);
    gemm_bt<4, float, float><<<dim3(2, C_ / 128, 4), dim3(256), 0, stream>>>(
        hilo, W1cat, nullptr, nullptr, nullptr, nullptr, Pmat, C_, 512, 2048, 2048);
    // GEMM1: M=16384, N=1024, K=1024 -> 128x8 = 1024 blocks (2-phase dbuf)
    gemm_bt<0, float, bf16_t><<<dim3(BT_ / 128, C_ / 128), dim3(256), 0, stream>>>(
        state, W1cat, nullptr, x, nullptr, Pmat, outb, C_, C_, C_, 2048);
    rms_rows_bf16<<<dim3(BT_ / 4), dim3(256), 0, stream>>>(outb, inv2);
    // y seed: b2b + outb (split-K GEMM2b accumulates on top)
    init_y<<<dim3(BT_ * C_ / (256 * 8)), dim3(256), 0, stream>>>(b2b, outb, y);
    for (int c = 0; c < BT_ / MCHUNK; c++) {
        const bf16_t* Ao = outb + (size_t)c * MCHUNK * C_;
        float* yo = y + (size_t)c * MCHUNK * C_;
        // GEMM2a: short K=1024 -> 2-phase dbuf 128x128, 64x32 = 2048 blocks
        gemm_bt<1, float, bf16_t><<<dim3(MCHUNK / 128, H_ / 128), dim3(256), 0, stream>>>(
            Ao, W2at, b2a, nullptr, inv2 + c * MCHUNK, nullptr, hbuf, H_, C_, C_, C_);
        // GEMM2b: long K=4096 -> 8-phase 256x256, split-K x2: (32,4,2) = 256 blocks
        gemm256<5, float, float><<<dim3(MCHUNK / 256, C_ / 256, 2), dim3(512), 0, stream>>>(
            hbuf, W2bt, nullptr, nullptr, yo, C_, H_ / 2, H_, H_);
    }
}

// Round 8
// 607.236 us; speedup vs baseline: 1.2981x; 1.1676x over previous
//
#include <hip/hip_runtime.h>

#define B_     4
#define T_     4096
#define C_     1024
#define H_     4096
#define BT_    (B_ * T_)
#define NCH_   64
#define CHLEN_ 64
#define MCHUNK 8192   // rows per h-chunk for GEMM2a/2b (2 chunks)

typedef __bf16 bf16_t;
typedef __bf16 bf16x8 __attribute__((ext_vector_type(8)));
typedef float  f32x4  __attribute__((ext_vector_type(4)));

__device__ __forceinline__ float hs_f(float v) {
    return fminf(fmaxf((v + 3.0f) * (1.0f / 6.0f), 0.0f), 1.0f) - 0.5f;
}

__device__ __forceinline__ void gld_lds16(const bf16_t* g, bf16_t* l) {
    __builtin_amdgcn_global_load_lds((const __attribute__((address_space(1))) void*)g,
                                     (__attribute__((address_space(3))) void*)l,
                                     16, 0, 0);
}

// ---------------------------------------------------------------------------
__global__ __launch_bounds__(256) void rms_rows_f32(const float* __restrict__ X,
                                                    float* __restrict__ inv) {
    const int wave = threadIdx.x >> 6, lane = threadIdx.x & 63;
    const int row = blockIdx.x * 4 + wave;
    const float* xr = X + (size_t)row * C_;
    float s = 0.0f;
    #pragma unroll
    for (int p = 0; p < 4; p++) {
        float4 v = *(const float4*)(xr + p * 256 + lane * 4);
        s += v.x * v.x + v.y * v.y + v.z * v.z + v.w * v.w;
    }
    #pragma unroll
    for (int o = 32; o > 0; o >>= 1) s += __shfl_down(s, o, 64);
    if (lane == 0) inv[row] = rsqrtf(s * (1.0f / C_) + 1e-6f);
}

__global__ __launch_bounds__(256) void rms_rows_bf16(const bf16_t* __restrict__ X,
                                                     float* __restrict__ inv) {
    const int wave = threadIdx.x >> 6, lane = threadIdx.x & 63;
    const int row = blockIdx.x * 4 + wave;
    const bf16_t* xr = X + (size_t)row * C_;
    bf16x8 v0 = *(const bf16x8*)(xr + lane * 8);
    bf16x8 v1 = *(const bf16x8*)(xr + 512 + lane * 8);
    float s = 0.0f;
    #pragma unroll
    for (int j = 0; j < 8; j++) {
        float a = (float)v0[j], b = (float)v1[j];
        s += a * a + b * b;
    }
    #pragma unroll
    for (int o = 32; o > 0; o >>= 1) s += __shfl_down(s, o, 64);
    if (lane == 0) inv[row] = rsqrtf(s * (1.0f / C_) + 1e-6f);
}

// ---------------------------------------------------------------------------
__global__ __launch_bounds__(256) void scan_emit_local(const float* __restrict__ X,
                                                       const float* __restrict__ inv1,
                                                       const float* __restrict__ nw,
                                                       bf16_t* __restrict__ state,
                                                       float* __restrict__ csum) {
    const int bch = blockIdx.x;
    const int b = bch >> 6, ch = bch & 63;
    const int c = blockIdx.y * 256 + threadIdx.x;
    const float wgt = nw[c];
    const int rbase = b * T_ + ch * CHLEN_;
    const size_t xbase = (size_t)rbase * C_ + c;
    float acc = 0.0f;
    for (int i = 0; i < CHLEN_; i++) {
        acc += hs_f(X[xbase + (size_t)i * C_] * inv1[rbase + i] * wgt);
        state[(size_t)(rbase + i) * C_ + c] = (bf16_t)acc;
    }
    csum[(size_t)bch * C_ + c] = acc;
}

__global__ __launch_bounds__(256) void scan_offsets_hilo(const float* __restrict__ csum,
                                                         bf16_t* __restrict__ hilo) {
    const int idx = blockIdx.x * 256 + threadIdx.x;   // b*1024 + c
    const int b = idx >> 10, c = idx & 1023;
    const size_t base = (size_t)b * NCH_ * C_ + c;
    float v[NCH_];
    #pragma unroll
    for (int ch = 0; ch < NCH_; ch++)
        v[ch] = csum[base + (size_t)ch * C_];
    float run = 0.0f;
    #pragma unroll
    for (int ch = 0; ch < NCH_; ch++) {
        const size_t row = (size_t)(b * NCH_ + ch) * 2048 + c;
        const bf16_t hi = (bf16_t)run;
        hilo[row] = hi;
        hilo[row + 1024] = (bf16_t)(run - (float)hi);
        run += v[ch];
    }
}

__global__ __launch_bounds__(256) void pmat_init(const float* __restrict__ b1,
                                                 float* __restrict__ Pmat) {
    const int i = blockIdx.x * 256 + threadIdx.x;
    Pmat[i] = b1[i & (C_ - 1)];
}

// ---------------------------------------------------------------------------
__global__ __launch_bounds__(256) void transpose_scale(const float* __restrict__ src,
                                                       bf16_t* __restrict__ dst,
                                                       int K, int N, int ldd, int dupOff,
                                                       const float* __restrict__ scale) {
    __shared__ float tile[32][33];
    const int n0 = blockIdx.x * 32, k0 = blockIdx.y * 32;
    const int tx = threadIdx.x & 31, ty = threadIdx.x >> 5;
    #pragma unroll
    for (int j = 0; j < 4; j++) {
        const int kk = ty + j * 8;
        float v = src[(size_t)(k0 + kk) * N + n0 + tx];
        if (scale) v *= scale[k0 + kk];
        tile[kk][tx] = v;
    }
    __syncthreads();
    #pragma unroll
    for (int j = 0; j < 4; j++) {
        const int nn = ty + j * 8;
        const bf16_t v = (bf16_t)tile[tx][nn];
        dst[(size_t)(n0 + nn) * ldd + k0 + tx] = v;
        if (dupOff) dst[(size_t)(n0 + nn) * ldd + dupOff + k0 + tx] = v;
    }
}

// ---------------------------------------------------------------------------
// 128x128 GEMM, 2-deep pipelined (R8):
//   prologue: STAGE(buf0,k0); STAGE(buf1,k0+32)
//   iter t:   vmcnt(4|0) -> s_barrier -> ds_read+MFMA(buf t&1) -> s_barrier
//             -> STAGE(buf t&1, k+64)
// Counted vmcnt (T4): loads for tile t issued 2 iterations early, never
// drained to 0 mid-loop (R6/R7 used __syncthreads whose vmcnt(0) drained the
// just-issued stage each iteration). Hazards: per-wave vmcnt(4) BEFORE
// barrier#1 => collectively buf t's stage retired; barrier#2 orders all
// waves' reads of buf t before its overwrite (reads are consumed by MFMA,
// which forces the lgkm wait, before barrier#2). Tail: vmcnt(0) last iter.
// LDS 2x16KB = 32 KiB -> up to 5 blocks/CU (cross-block overlap retained).
//
// LDS swizzle (T2, R6-verified: SQ_LDS_BANK_CONFLICT 8.4M -> 0): rows are
// 64B = 4x16B slots; phys slot s' = s ^ ((row>>1)&3). LDS dest linear
// (gld_lds uniform+lane*16), GLOBAL source col pre-swizzled, ds_read applies
// the same XOR (rule #21). Bitwise-same numerics (ascending K 32-groups).
//
// MODE 0: out bf16 = hs(acc + pmat[(m>>6)*N+n]) * xf32[m*N+n]   (GEMM1)
// MODE 1: out bf16 = relu(rowscale[m]*acc + bias[n])            (GEMM2a)
// MODE 2: out f32  = acc + bias[n] + (f32)extra_bf16[m*N+n]     (GEMM2b)
// MODE 4: atomicAdd(out f32, acc)                               (split-K P-GEMM)
// ---------------------------------------------------------------------------
template <int MODE, typename ET, typename OT>
__global__ __launch_bounds__(256) void gemm_bt(const bf16_t* __restrict__ A,
                                               const bf16_t* __restrict__ Bt,
                                               const float* __restrict__ bias,
                                               const ET* __restrict__ extra,
                                               const float* __restrict__ rowscale,
                                               const float* __restrict__ pmat,
                                               OT* __restrict__ Cmat,
                                               int N, int K, int lda, int ldb) {
    __shared__ __align__(16) bf16_t As[2][128 * 32];
    __shared__ __align__(16) bf16_t Bs[2][128 * 32];
    const int tid = threadIdx.x;

    const int nwgx = gridDim.x;
    const int flat0 = blockIdx.y * nwgx + blockIdx.x;
    int mTile, nTile;
    if ((nwgx & 7) == 0) {                  // XCD m-slice mapping (R3 win)
        const int xcd = flat0 & 7;
        const int loc = flat0 >> 3;
        const int mpx = nwgx >> 3;
        mTile = xcd * mpx + (loc % mpx);
        nTile = loc / mpx;
    } else {
        mTile = blockIdx.x;
        nTile = blockIdx.y;
    }
    const int mBase = mTile * 128;
    const int nBase = nTile * 128;
    const size_t kOff = (size_t)blockIdx.z * K;

    const int wave = tid >> 6;
    const int lane = tid & 63;
    const int waveM = (wave & 1) * 64;
    const int waveN = (wave >> 1) * 64;
    const int lr = lane & 15;
    const int lq = lane >> 4;

    f32x4 acc[4][4] = {};

    // Staging: thread covers elements e0=tid*8 and e1=2048+tid*8 (LDS linear,
    // wave-uniform + lane*16). Source col pre-swizzled: logical slot for phys
    // slot sp at row r is sp ^ ((r>>1)&3).
    const int e0 = tid * 8;
    const int r0 = e0 >> 5, c0 = (((e0 >> 3) & 3) ^ ((r0 >> 1) & 3)) << 3;
    const int e1 = 2048 + tid * 8;
    const int r1 = e1 >> 5, c1 = (((e1 >> 3) & 3) ^ ((r1 >> 1) & 3)) << 3;

    const bf16_t* Ag0 = A + (size_t)(mBase + r0) * lda + kOff + c0;
    const bf16_t* Ag1 = A + (size_t)(mBase + r1) * lda + kOff + c1;
    const bf16_t* Bg0 = Bt + (size_t)(nBase + r0) * ldb + kOff + c0;
    const bf16_t* Bg1 = Bt + (size_t)(nBase + r1) * ldb + kOff + c1;

    auto stage = [&](int buf, int kb) {
        gld_lds16(Ag0 + kb, As[buf] + e0);
        gld_lds16(Ag1 + kb, As[buf] + e1);
        gld_lds16(Bg0 + kb, Bs[buf] + e0);
        gld_lds16(Bg1 + kb, Bs[buf] + e1);
    };

    stage(0, 0);
    if (32 < K) stage(1, 32);

    int cur = 0;
    for (int kb = 0; kb < K; kb += 32) {
        if (kb + 32 < K) asm volatile("s_waitcnt vmcnt(4)" ::: "memory");
        else             asm volatile("s_waitcnt vmcnt(0)" ::: "memory");
        __builtin_amdgcn_s_barrier();       // buf cur staged for all waves

        bf16x8 af[4], bfr[4];
        #pragma unroll
        for (int mi = 0; mi < 4; mi++) {
            const int R = waveM + mi * 16 + lr;
            af[mi] = *(const bf16x8*)(As[cur] + R * 32 + ((lq ^ ((R >> 1) & 3)) << 3));
        }
        #pragma unroll
        for (int ni = 0; ni < 4; ni++) {
            const int R = waveN + ni * 16 + lr;
            bfr[ni] = *(const bf16x8*)(Bs[cur] + R * 32 + ((lq ^ ((R >> 1) & 3)) << 3));
        }
        #pragma unroll
        for (int mi = 0; mi < 4; mi++)
            #pragma unroll
            for (int ni = 0; ni < 4; ni++)
                acc[mi][ni] = __builtin_amdgcn_mfma_f32_16x16x32_bf16(
                    af[mi], bfr[ni], acc[mi][ni], 0, 0, 0);

        __builtin_amdgcn_s_barrier();       // all waves done reading buf cur
        if (kb + 64 < K) stage(cur, kb + 64);   // overwrite cur for iter t+2
        cur ^= 1;
    }

    // Epilogue. C/D layout: col(n)=lane&15, row(m)=(lane>>4)*4+reg.
    #pragma unroll
    for (int ni = 0; ni < 4; ni++) {
        const int n = nBase + waveN + ni * 16 + lr;
        const float bz = (MODE == 1 || MODE == 2) ? bias[n] : 0.0f;
        #pragma unroll
        for (int mi = 0; mi < 4; mi++) {
            #pragma unroll
            for (int r = 0; r < 4; r++) {
                const int m = mBase + waveM + mi * 16 + lq * 4 + r;
                float v = acc[mi][ni][r];
                if (MODE == 0) {
                    v = hs_f(v + pmat[(size_t)(m >> 6) * N + n]) * (float)extra[(size_t)m * N + n];
                    Cmat[(size_t)m * N + n] = (OT)v;
                } else if (MODE == 1) {
                    v = fmaxf(rowscale[m] * v + bz, 0.0f);
                    Cmat[(size_t)m * N + n] = (OT)v;
                } else if (MODE == 2) {
                    v = v + bz + (float)extra[(size_t)m * N + n];
                    Cmat[(size_t)m * N + n] = (OT)v;
                } else {
                    atomicAdd((float*)&Cmat[(size_t)m * N + n], v);
                }
            }
        }
    }
}

// ---------------------------------------------------------------------------
extern "C" void kernel_launch(void* const* d_in, const int* in_sizes, int n_in,
                              void* d_out, int out_size, void* d_ws, size_t ws_size,
                              hipStream_t stream) {
    const float* x   = (const float*)d_in[0];
    const float* n1w = (const float*)d_in[1];
    const float* w1  = (const float*)d_in[2];
    const float* b1  = (const float*)d_in[3];
    const float* n2w = (const float*)d_in[4];
    const float* w2a = (const float*)d_in[5];
    const float* b2a = (const float*)d_in[6];
    const float* w2b = (const float*)d_in[7];
    const float* b2b = (const float*)d_in[8];
    float* y = (float*)d_out;

    char* w = (char*)d_ws;
    float*  inv1  = (float*)(w + 0);
    float*  inv2  = (float*)(w + 65536);
    float*  csum  = (float*)(w + 131072);
    bf16_t* hilo  = (bf16_t*)(w + 1179648);
    float*  Pmat  = (float*)(w + 2228224);
    bf16_t* W1cat = (bf16_t*)(w + 5373952);
    bf16_t* W2at  = (bf16_t*)(w + 9568256);
    bf16_t* W2bt  = (bf16_t*)(w + 17956864);
    bf16_t* outb  = (bf16_t*)(w + 26345472);
    bf16_t* state = (bf16_t*)(w + 59899904);
    bf16_t* hbuf  = state;

    rms_rows_f32<<<dim3(BT_ / 4), dim3(256), 0, stream>>>(x, inv1);
    scan_emit_local<<<dim3(B_ * NCH_, C_ / 256), dim3(256), 0, stream>>>(x, inv1, n1w, state, csum);
    scan_offsets_hilo<<<dim3(B_ * C_ / 256), dim3(256), 0, stream>>>(csum, hilo);
    transpose_scale<<<dim3(C_ / 32, C_ / 32), dim3(256), 0, stream>>>(
        w1, W1cat, C_, C_, 2048, 1024, nullptr);
    transpose_scale<<<dim3(H_ / 32, C_ / 32), dim3(256), 0, stream>>>(
        w2a, W2at, C_, H_, C_, 0, n2w);
    transpose_scale<<<dim3(C_ / 32, H_ / 32), dim3(256), 0, stream>>>(
        w2b, W2bt, H_, C_, H_, 0, nullptr);
    pmat_init<<<dim3(256 * C_ / 256), dim3(256), 0, stream>>>(b1, Pmat);
    gemm_bt<4, float, float><<<dim3(2, C_ / 128, 4), dim3(256), 0, stream>>>(
        hilo, W1cat, nullptr, nullptr, nullptr, nullptr, Pmat, C_, 512, 2048, 2048);
    // GEMM1: M=16384, N=1024, K=1024 -> 128x8 = 1024 blocks
    gemm_bt<0, float, bf16_t><<<dim3(BT_ / 128, C_ / 128), dim3(256), 0, stream>>>(
        state, W1cat, nullptr, x, nullptr, Pmat, outb, C_, C_, C_, 2048);
    rms_rows_bf16<<<dim3(BT_ / 4), dim3(256), 0, stream>>>(outb, inv2);
    for (int c = 0; c < BT_ / MCHUNK; c++) {
        const bf16_t* Ao = outb + (size_t)c * MCHUNK * C_;
        float* yo = y + (size_t)c * MCHUNK * C_;
        // GEMM2a: M=8192, N=4096, K=1024 -> 64x32 = 2048 blocks
        gemm_bt<1, float, bf16_t><<<dim3(MCHUNK / 128, H_ / 128), dim3(256), 0, stream>>>(
            Ao, W2at, b2a, nullptr, inv2 + c * MCHUNK, nullptr, hbuf, H_, C_, C_, C_);
        // GEMM2b: M=8192, N=1024, K=4096 full-K -> 64x8 = 512 blocks, plain store
        gemm_bt<2, bf16_t, float><<<dim3(MCHUNK / 128, C_ / 128), dim3(256), 0, stream>>>(
            hbuf, W2bt, b2b, Ao, nullptr, nullptr, yo, C_, H_, H_, H_);
    }
}